// Round 4
// baseline (4499.978 us; speedup 1.0000x reference)
//
#include <hip/hip_runtime.h>
#include <stdint.h>

namespace {

constexpr int B_   = 512;
constexpr int T_   = 512;
constexpr int IN_  = 6;
constexpr int H_   = 64;
constexpr int HH_  = 128;
constexpr int OUT_ = 8;

typedef _Float16 f16x2 __attribute__((ext_vector_type(2)));

__device__ __forceinline__ float dot2f(uint32_t w, uint32_t z, float acc) {
    return __builtin_amdgcn_fdot2(__builtin_bit_cast(f16x2, w),
                                  __builtin_bit_cast(f16x2, z), acc, false);
}

__device__ __forceinline__ uint32_t pack2f(float a, float b) {
    f16x2 p;
    p[0] = (_Float16)a;
    p[1] = (_Float16)b;
    return __builtin_bit_cast(uint32_t, p);
}

// sum across the 4 lanes of a quad (kq = lane&3) via DPP quad_perm — pure VALU,
// no LDS pipe. All 4 lanes end with the full sum.
__device__ __forceinline__ float qsum4(float v) {
    int y = __builtin_amdgcn_mov_dpp(__builtin_bit_cast(int, v), 0xB1, 0xF, 0xF, true); // [1,0,3,2] xor1
    v += __builtin_bit_cast(float, y);
    y = __builtin_amdgcn_mov_dpp(__builtin_bit_cast(int, v), 0x4E, 0xF, 0xF, true);     // [2,3,0,1] xor2
    return v + __builtin_bit_cast(float, y);
}

__device__ __forceinline__ float tanh_fast(float v) {
    float ax = fabsf(v);
    float e  = __expf(2.0f * ax);
    float r  = 1.0f - 2.0f / (e + 1.0f);
    return copysignf(r, v);
}

// One workgroup (512 threads) per batch element.
//   thread t: column c = t>>2, k-quarter kq = t&3.
//   88 packed-f16-pair weight u32 per thread -> fits 128 arch VGPRs (no AGPR copies).
//   quad reduction via DPP; activations stored as f16 via ds_write_b16.
__global__ __launch_bounds__(512, 4) void cde_kernel(
    const float* __restrict__ x,
    const float* __restrict__ W_init, const float* __restrict__ b_init,
    const float* __restrict__ W_in,   const float* __restrict__ b_in,
    const float* __restrict__ W_h1,   const float* __restrict__ b_h1,
    const float* __restrict__ W_h2,   const float* __restrict__ b_h2,
    const float* __restrict__ W_out,  const float* __restrict__ b_out,
    const float* __restrict__ W_fin,  const float* __restrict__ b_fin,
    float* __restrict__ out)
{
    const int b  = blockIdx.x;
    const int t  = threadIdx.x;
    const int c  = t >> 2;      // 0..127
    const int kq = t & 3;       // k-quarter

    __shared__ alignas(16) uint32_t hinu[H_ / 2];    // 64 f16 (vf input h)
    __shared__ alignas(16) uint32_t zAu[HH_ / 2];    // 128 f16 ping
    __shared__ alignas(16) uint32_t zBu[HH_ / 2];    // 128 f16 pong
    __shared__ alignas(16) float    pp[H_][8];       // tanh(A)*dx, padded rows
    __shared__ float dxs[IN_];
    __shared__ float hbuf[H_];
    __shared__ float wfin_s[H_ * OUT_];
    __shared__ float bfin_s[OUT_];
    __shared__ float bo_s[3 * HH_];                  // b_out (384)

    // ---- register-resident f16 weights (k-quarter slice) ----
    uint32_t w1[8], w2[16], w3[16], w4[48];
    #pragma unroll
    for (int i = 0; i < 8; ++i) {
        int k = kq * 16 + 2 * i;
        w1[i] = pack2f(W_in[k * HH_ + c], W_in[(k + 1) * HH_ + c]);
    }
    #pragma unroll
    for (int i = 0; i < 16; ++i) {
        int k = kq * 32 + 2 * i;
        w2[i] = pack2f(W_h1[k * HH_ + c], W_h1[(k + 1) * HH_ + c]);
        w3[i] = pack2f(W_h2[k * HH_ + c], W_h2[(k + 1) * HH_ + c]);
    }
    #pragma unroll
    for (int j = 0; j < 3; ++j) {
        const int cc = c + 128 * j;
        #pragma unroll
        for (int i = 0; i < 16; ++i) {
            int k = kq * 32 + 2 * i;
            w4[j * 16 + i] = pack2f(W_out[k * 384 + cc], W_out[(k + 1) * 384 + cc]);
        }
    }
    const float bin_r = b_in[c];
    const float bh1_r = b_h1[c];
    const float bh2_r = b_h2[c];
    // pp/dxs addressing for the 3 owned A-columns (col j -> A[j/6][j%6])
    const int m0 = c % 6,          m1 = (c + 128) % 6,          m2 = (c + 256) % 6;
    const int o0 = (c / 6) * 8 + m0, o1 = ((c + 128) / 6) * 8 + m1, o2 = ((c + 256) / 6) * 8 + m2;

    wfin_s[t < H_ * OUT_ ? t : 0] = W_fin[t < H_ * OUT_ ? t : 0]; // t<512 == all
    if (t < OUT_)     bfin_s[t] = b_fin[t];
    if (t < 3 * HH_)  bo_s[t]   = b_out[t];

    const size_t xbase = (size_t)b * T_ * IN_;
    const size_t obase = (size_t)b * T_ * OUT_;

    float xa = 0.f, xb = 0.f;
    if (t < IN_) {
        xa = x[xbase + t];
        xb = x[xbase + IN_ + t];
    }

    // ---- h0 = x[:,0] @ W_init + b_init (wave 0) ----
    float h_reg = 0.f, hacc = 0.f;
    if (t < H_) {
        float s = b_init[t];
        #pragma unroll
        for (int i = 0; i < IN_; ++i) s += x[xbase + i] * W_init[i * H_ + t];
        h_reg = s;
        hbuf[t] = s;
        ((_Float16*)hinu)[t] = (_Float16)s;
    }
    __syncthreads();

    // out for t = 0
    if (t < 64) {
        int o = t & 7, part = t >> 3;
        float s = 0.f;
        #pragma unroll
        for (int j = 0; j < 8; ++j) s += hbuf[part * 8 + j] * wfin_s[(part * 8 + j) * OUT_ + o];
        s += __shfl_xor(s, 8);
        s += __shfl_xor(s, 16);
        s += __shfl_xor(s, 32);
        if (part == 0) out[obase + o] = s + bfin_s[o];
    }

    for (int step = 0; step < T_ - 1; ++step) {
        // write this step's dX; readers (G4) are >=3 barriers later, previous
        // step's readers were all before the last hin barrier.
        if (t < IN_) {
            dxs[t] = xb - xa;
            xa = xb;
            if (step + 2 < T_) xb = x[xbase + (size_t)(step + 2) * IN_ + t];
        }

        #pragma unroll
        for (int s4 = 0; s4 < 4; ++s4) {
            // ---- G1: h(64) -> z1(128) into zA ----
            {
                const uint32_t* hp = hinu + kq * 8;
                uint4 q0 = *reinterpret_cast<const uint4*>(hp);
                uint4 q1 = *reinterpret_cast<const uint4*>(hp + 4);
                float a = 0.f, bq = 0.f;
                a = dot2f(w1[0], q0.x, a); bq = dot2f(w1[1], q0.y, bq);
                a = dot2f(w1[2], q0.z, a); bq = dot2f(w1[3], q0.w, bq);
                a = dot2f(w1[4], q1.x, a); bq = dot2f(w1[5], q1.y, bq);
                a = dot2f(w1[6], q1.z, a); bq = dot2f(w1[7], q1.w, bq);
                float z = fmaxf(bin_r + qsum4(a + bq), 0.f);
                if (kq == 0) ((_Float16*)zAu)[c] = (_Float16)z;
            }
            __syncthreads();

            // ---- G2: zA -> z2 into zB ----
            {
                const uint32_t* zp = zAu + kq * 16;
                uint4 q0 = *reinterpret_cast<const uint4*>(zp);
                uint4 q1 = *reinterpret_cast<const uint4*>(zp + 4);
                float a = 0.f, bq = 0.f;
                a = dot2f(w2[0], q0.x, a); bq = dot2f(w2[1], q0.y, bq);
                a = dot2f(w2[2], q0.z, a); bq = dot2f(w2[3], q0.w, bq);
                a = dot2f(w2[4], q1.x, a); bq = dot2f(w2[5], q1.y, bq);
                a = dot2f(w2[6], q1.z, a); bq = dot2f(w2[7], q1.w, bq);
                uint4 q2 = *reinterpret_cast<const uint4*>(zp + 8);
                uint4 q3 = *reinterpret_cast<const uint4*>(zp + 12);
                a = dot2f(w2[8],  q2.x, a); bq = dot2f(w2[9],  q2.y, bq);
                a = dot2f(w2[10], q2.z, a); bq = dot2f(w2[11], q2.w, bq);
                a = dot2f(w2[12], q3.x, a); bq = dot2f(w2[13], q3.y, bq);
                a = dot2f(w2[14], q3.z, a); bq = dot2f(w2[15], q3.w, bq);
                float z = fmaxf(bh1_r + qsum4(a + bq), 0.f);
                if (kq == 0) ((_Float16*)zBu)[c] = (_Float16)z;
            }
            __syncthreads();

            // ---- G3: zB -> z3 into zA ----
            {
                const uint32_t* zp = zBu + kq * 16;
                uint4 q0 = *reinterpret_cast<const uint4*>(zp);
                uint4 q1 = *reinterpret_cast<const uint4*>(zp + 4);
                float a = 0.f, bq = 0.f;
                a = dot2f(w3[0], q0.x, a); bq = dot2f(w3[1], q0.y, bq);
                a = dot2f(w3[2], q0.z, a); bq = dot2f(w3[3], q0.w, bq);
                a = dot2f(w3[4], q1.x, a); bq = dot2f(w3[5], q1.y, bq);
                a = dot2f(w3[6], q1.z, a); bq = dot2f(w3[7], q1.w, bq);
                uint4 q2 = *reinterpret_cast<const uint4*>(zp + 8);
                uint4 q3 = *reinterpret_cast<const uint4*>(zp + 12);
                a = dot2f(w3[8],  q2.x, a); bq = dot2f(w3[9],  q2.y, bq);
                a = dot2f(w3[10], q2.z, a); bq = dot2f(w3[11], q2.w, bq);
                a = dot2f(w3[12], q3.x, a); bq = dot2f(w3[13], q3.y, bq);
                a = dot2f(w3[14], q3.z, a); bq = dot2f(w3[15], q3.w, bq);
                float z = fmaxf(bh2_r + qsum4(a + bq), 0.f);
                if (kq == 0) ((_Float16*)zAu)[c] = (_Float16)z;
            }
            __syncthreads();

            // ---- G4: z3 -> 384 cols, tanh, * dX ----
            {
                const uint32_t* zp = zAu + kq * 16;
                uint4 q0 = *reinterpret_cast<const uint4*>(zp);
                uint4 q1 = *reinterpret_cast<const uint4*>(zp + 4);
                float a0 = 0.f, a1 = 0.f, a2 = 0.f;
                #pragma unroll
                for (int i = 0; i < 4; ++i) {
                    uint32_t zi = (&q0.x)[i];
                    a0 = dot2f(w4[i],      zi, a0);
                    a1 = dot2f(w4[16 + i], zi, a1);
                    a2 = dot2f(w4[32 + i], zi, a2);
                }
                #pragma unroll
                for (int i = 0; i < 4; ++i) {
                    uint32_t zi = (&q1.x)[i];
                    a0 = dot2f(w4[4 + i],      zi, a0);
                    a1 = dot2f(w4[20 + i], zi, a1);
                    a2 = dot2f(w4[36 + i], zi, a2);
                }
                uint4 q2 = *reinterpret_cast<const uint4*>(zp + 8);
                uint4 q3 = *reinterpret_cast<const uint4*>(zp + 12);
                #pragma unroll
                for (int i = 0; i < 4; ++i) {
                    uint32_t zi = (&q2.x)[i];
                    a0 = dot2f(w4[8 + i],      zi, a0);
                    a1 = dot2f(w4[24 + i], zi, a1);
                    a2 = dot2f(w4[40 + i], zi, a2);
                }
                #pragma unroll
                for (int i = 0; i < 4; ++i) {
                    uint32_t zi = (&q3.x)[i];
                    a0 = dot2f(w4[12 + i],     zi, a0);
                    a1 = dot2f(w4[28 + i], zi, a1);
                    a2 = dot2f(w4[44 + i], zi, a2);
                }
                a0 = qsum4(a0);
                a1 = qsum4(a1);
                a2 = qsum4(a2);
                if (kq == 0) {
                    float* ppf = &pp[0][0];
                    ppf[o0] = tanh_fast(bo_s[c]       + a0) * dxs[m0];
                    ppf[o1] = tanh_fast(bo_s[c + 128] + a1) * dxs[m1];
                    ppf[o2] = tanh_fast(bo_s[c + 256] + a2) * dxs[m2];
                }
            }
            __syncthreads();

            // ---- k = A @ dX; RK4 bookkeeping; next vf input (wave 0) ----
            if (t < H_) {
                float4 p0 = *reinterpret_cast<const float4*>(&pp[t][0]);
                float4 p1 = *reinterpret_cast<const float4*>(&pp[t][4]);
                float kv = p0.x + p0.y + p0.z + p0.w + p1.x + p1.y;
                hacc += ((s4 == 1 || s4 == 2) ? 2.0f : 1.0f) * kv;
                float hs;
                if (s4 < 3) {
                    hs = h_reg + ((s4 == 2) ? 1.0f : 0.5f) * kv;
                } else {
                    h_reg += hacc * (1.0f / 6.0f);
                    hacc = 0.f;
                    hbuf[t] = h_reg;
                    hs = h_reg;
                }
                ((_Float16*)hinu)[t] = (_Float16)hs;
            }
            __syncthreads();
        }

        // ---- out for tt = step+1 (wave 0) ----
        if (t < 64) {
            int o = t & 7, part = t >> 3;
            float s = 0.f;
            #pragma unroll
            for (int j = 0; j < 8; ++j) s += hbuf[part * 8 + j] * wfin_s[(part * 8 + j) * OUT_ + o];
            s += __shfl_xor(s, 8);
            s += __shfl_xor(s, 16);
            s += __shfl_xor(s, 32);
            if (part == 0) out[obase + (size_t)(step + 1) * OUT_ + o] = s + bfin_s[o];
        }
    }
}

} // namespace

extern "C" void kernel_launch(void* const* d_in, const int* in_sizes, int n_in,
                              void* d_out, int out_size, void* d_ws, size_t ws_size,
                              hipStream_t stream) {
    const float* x      = (const float*)d_in[0];
    const float* W_init = (const float*)d_in[1];
    const float* b_init = (const float*)d_in[2];
    const float* W_in   = (const float*)d_in[3];
    const float* b_in   = (const float*)d_in[4];
    const float* W_h1   = (const float*)d_in[5];
    const float* b_h1   = (const float*)d_in[6];
    const float* W_h2   = (const float*)d_in[7];
    const float* b_h2   = (const float*)d_in[8];
    const float* W_out  = (const float*)d_in[9];
    const float* b_out  = (const float*)d_in[10];
    const float* W_fin  = (const float*)d_in[11];
    const float* b_fin  = (const float*)d_in[12];
    float* out = (float*)d_out;

    cde_kernel<<<dim3(B_), dim3(512), 0, stream>>>(
        x, W_init, b_init, W_in, b_in, W_h1, b_h1, W_h2, b_h2,
        W_out, b_out, W_fin, b_fin, out);
}